// Round 1
// baseline (1963.580 us; speedup 1.0000x reference)
//
#include <hip/hip_runtime.h>
#include <hip/hip_bf16.h>

// Problem: B=32, L=2048, H=1024, K=3H=3072, M=B*L=65536
// ref: t = trg @ fc_w^T + fc_b  [M, H]
//      norm1 = ||t||_2 over H   [B, L]
//      w = softmax(norm1, axis=L)
//      summ = sum_l w * t = fc_w @ (sum_l w*trg) + fc_b   (since sum_l w == 1)
// out = concat(summ [32*1024], norm1 [32*2048]) fp32

#define B_ 32
#define L_ 2048
#define H_ 1024
#define K_ 3072
#define M_ 65536

typedef __attribute__((ext_vector_type(8))) short short8;
typedef __attribute__((ext_vector_type(4))) float floatx4;

#define LDST 40  // LDS row stride in bf16 elems (32 + 8 pad): keeps 16B align, 2-way banks

__device__ __forceinline__ unsigned int pack_bf16x2(float a, float b) {
    __hip_bfloat162 h = __float22bfloat162_rn(make_float2(a, b));
    return *reinterpret_cast<unsigned int*>(&h);
}

// ---------------- K1: GEMM (bf16 MFMA) fused with row sum-of-squares ----------------
// grid 4096 = 512 row-tiles x 8 col-tiles (col fastest -> 8 siblings share A tile via L3)
// block 256 = 4 waves in 2x2; wave computes 64x64 via 4x4 frags of 16x16x32.
__global__ void __launch_bounds__(256) gemm_norm_kernel(const float* __restrict__ trg,
                                                        const float* __restrict__ fcw,
                                                        float* __restrict__ normsq) {
    __shared__ unsigned short As[128 * LDST];
    __shared__ unsigned short Bs[128 * LDST];

    const int tid  = threadIdx.x;
    const int bid  = blockIdx.x;
    const int nblk = bid & 7;
    const int mblk = bid >> 3;
    const int R0   = mblk * 128;
    const int N0   = nblk * 128;
    const int wv   = tid >> 6;
    const int lane = tid & 63;
    const int wr   = wv >> 1;   // wave row (0..1)
    const int wc   = wv & 1;    // wave col (0..1)
    const int q    = lane >> 4; // quad 0..3
    const int ln   = lane & 15;

    floatx4 acc[4][4] = {};

    // staging: each thread loads 4x float4 for A and B per K-step (32 floats/row, 8 chunks)
    const int srow = tid >> 3;   // 0..31
    const int skc  = tid & 7;    // float4 chunk in row
    const float* ap = trg + (size_t)(R0 + srow) * K_ + skc * 4;
    const float* bp = fcw + (size_t)(N0 + srow) * K_ + skc * 4;
    unsigned short* AsW = &As[srow * LDST + skc * 4];
    unsigned short* BsW = &Bs[srow * LDST + skc * 4];

    const unsigned short* Af = &As[(wr * 64 + ln) * LDST + q * 8];
    const unsigned short* Bf = &Bs[(wc * 64 + ln) * LDST + q * 8];

    float4 ra[4], rb[4];
#pragma unroll
    for (int s = 0; s < 4; ++s) {
        ra[s] = *(const float4*)(ap + (size_t)(s * 32) * K_);
        rb[s] = *(const float4*)(bp + (size_t)(s * 32) * K_);
    }

    for (int step = 0; step < 96; ++step) {
        __syncthreads();
#pragma unroll
        for (int s = 0; s < 4; ++s) {
            uint2 ua, ub;
            ua.x = pack_bf16x2(ra[s].x, ra[s].y);
            ua.y = pack_bf16x2(ra[s].z, ra[s].w);
            ub.x = pack_bf16x2(rb[s].x, rb[s].y);
            ub.y = pack_bf16x2(rb[s].z, rb[s].w);
            *(uint2*)(AsW + s * 32 * LDST) = ua;
            *(uint2*)(BsW + s * 32 * LDST) = ub;
        }
        // software-pipeline: issue next tile's global loads; latency hides under MFMA
        if (step < 95) {
            const int kk = (step + 1) * 32;
#pragma unroll
            for (int s = 0; s < 4; ++s) {
                ra[s] = *(const float4*)(ap + (size_t)(s * 32) * K_ + kk);
                rb[s] = *(const float4*)(bp + (size_t)(s * 32) * K_ + kk);
            }
        }
        __syncthreads();

        short8 af[4], bf[4];
#pragma unroll
        for (int i = 0; i < 4; ++i) {
            af[i] = *(const short8*)(Af + i * 16 * LDST);
            bf[i] = *(const short8*)(Bf + i * 16 * LDST);
        }
#pragma unroll
        for (int mi = 0; mi < 4; ++mi)
#pragma unroll
            for (int ni = 0; ni < 4; ++ni)
                acc[mi][ni] = __builtin_amdgcn_mfma_f32_16x16x32_bf16(af[mi], bf[ni],
                                                                      acc[mi][ni], 0, 0, 0);
    }

    // epilogue: per-row sum of squares over this block's 128 columns.
    // D layout: col = lane&15, row = q*4 + reg  (16x16 tile)
    float* nsq = normsq + R0;
#pragma unroll
    for (int mi = 0; mi < 4; ++mi) {
#pragma unroll
        for (int r = 0; r < 4; ++r) {
            float s = 0.0f;
#pragma unroll
            for (int ni = 0; ni < 4; ++ni) {
                float v = acc[mi][ni][r];
                s += v * v;
            }
            // reduce across the 16 lanes (cols) of this quad
            s += __shfl_xor(s, 1);
            s += __shfl_xor(s, 2);
            s += __shfl_xor(s, 4);
            s += __shfl_xor(s, 8);
            if (ln == 0) atomicAdd(&nsq[wr * 64 + mi * 16 + q * 4 + r], s);
        }
    }
}

// ---------------- K2: norm1 = sqrt(normsq); per-batch softmax stats ----------------
__global__ void __launch_bounds__(256) softmax_stats_kernel(const float* __restrict__ normsq,
                                                            float* __restrict__ norm1,
                                                            float* __restrict__ bstats) {
    const int b = blockIdx.x;
    const int t = threadIdx.x;
    __shared__ float red[256];

    float vals[8];
    float mx = -1e30f;
#pragma unroll
    for (int i = 0; i < 8; ++i) {
        float v = sqrtf(normsq[b * L_ + i * 256 + t]);
        vals[i] = v;
        norm1[b * L_ + i * 256 + t] = v;
        mx = fmaxf(mx, v);
    }
    red[t] = mx;
    __syncthreads();
    for (int s = 128; s > 0; s >>= 1) {
        if (t < s) red[t] = fmaxf(red[t], red[t + s]);
        __syncthreads();
    }
    mx = red[0];
    __syncthreads();

    float sm = 0.0f;
#pragma unroll
    for (int i = 0; i < 8; ++i) sm += expf(vals[i] - mx);
    red[t] = sm;
    __syncthreads();
    for (int s = 128; s > 0; s >>= 1) {
        if (t < s) red[t] += red[t + s];
        __syncthreads();
    }
    if (t == 0) {
        bstats[b * 2 + 0] = mx;
        bstats[b * 2 + 1] = 1.0f / red[0];
    }
}

// ---------------- K3: p[b,k] = sum_l w[b,l] * trg[b,l,k] ----------------
// grid 32*24: per block one b, one of 8 L-chunks (256 l), one of 3 K-chunks (1024 floats)
__global__ void __launch_bounds__(256) pool_kernel(const float* __restrict__ trg,
                                                   const float* __restrict__ norm1,
                                                   const float* __restrict__ bstats,
                                                   float* __restrict__ p) {
    const int t  = threadIdx.x;
    const int b  = blockIdx.x / 24;
    const int r  = blockIdx.x % 24;
    const int lc = r / 3;
    const int kc = r % 3;
    const int l0 = lc * 256;

    __shared__ float wl[256];
    const float mx   = bstats[b * 2 + 0];
    const float sinv = bstats[b * 2 + 1];
    wl[t] = expf(norm1[b * L_ + l0 + t] - mx) * sinv;
    __syncthreads();

    const int k = kc * 1024 + t * 4;
    const float* tp = trg + (size_t)b * L_ * K_ + (size_t)l0 * K_ + k;
    float4 acc = {0.0f, 0.0f, 0.0f, 0.0f};
    for (int i = 0; i < 256; ++i) {
        float4 v = *(const float4*)(tp + (size_t)i * K_);
        float w = wl[i];
        acc.x += w * v.x;
        acc.y += w * v.y;
        acc.z += w * v.z;
        acc.w += w * v.w;
    }
    float* pp = p + b * K_ + k;
    atomicAdd(&pp[0], acc.x);
    atomicAdd(&pp[1], acc.y);
    atomicAdd(&pp[2], acc.z);
    atomicAdd(&pp[3], acc.w);
}

// ---------------- K4: summ[b,h] = fc_b[h] + fc_w[h,:] . p[b,:] ----------------
// grid 128: b = bx>>2, h-chunk of 256
__global__ void __launch_bounds__(256) summ_kernel(const float* __restrict__ fcw,
                                                   const float* __restrict__ fcb,
                                                   const float* __restrict__ p,
                                                   float* __restrict__ summ) {
    __shared__ float ps[K_];
    const int b  = blockIdx.x >> 2;
    const int hc = blockIdx.x & 3;
    const int t  = threadIdx.x;

    for (int i = t; i < K_ / 4; i += 256)
        ((float4*)ps)[i] = ((const float4*)(p + (size_t)b * K_))[i];
    __syncthreads();

    const int h = hc * 256 + t;
    const float4* wrow = (const float4*)(fcw + (size_t)h * K_);
    float acc = fcb[h];
    for (int i = 0; i < K_ / 4; ++i) {
        float4 wv = wrow[i];
        float4 pv = ((const float4*)ps)[i];
        acc += wv.x * pv.x + wv.y * pv.y + wv.z * pv.z + wv.w * pv.w;
    }
    summ[b * H_ + h] = acc;
}

extern "C" void kernel_launch(void* const* d_in, const int* in_sizes, int n_in,
                              void* d_out, int out_size, void* d_ws, size_t ws_size,
                              hipStream_t stream) {
    (void)in_sizes; (void)n_in; (void)out_size; (void)ws_size;
    const float* trg = (const float*)d_in[0];
    // d_in[1] = src, unused (n_layers == 0)
    const float* fcw = (const float*)d_in[2];
    const float* fcb = (const float*)d_in[3];

    float* out   = (float*)d_out;
    float* summ  = out;            // [32*1024]
    float* norm1 = out + B_ * H_;  // [32*2048]

    float* normsq = (float*)d_ws;        // M_ floats
    float* p      = normsq + M_;         // B_*K_ floats
    float* bstats = p + B_ * K_;         // 64 floats

    // ws is poisoned 0xAA before every call: zero the accumulators
    hipMemsetAsync(d_ws, 0, (size_t)(M_ + B_ * K_ + 64) * sizeof(float), stream);

    hipLaunchKernelGGL(gemm_norm_kernel, dim3(4096), dim3(256), 0, stream, trg, fcw, normsq);
    hipLaunchKernelGGL(softmax_stats_kernel, dim3(B_), dim3(256), 0, stream, normsq, norm1, bstats);
    hipLaunchKernelGGL(pool_kernel, dim3(B_ * 24), dim3(256), 0, stream, trg, norm1, bstats, p);
    hipLaunchKernelGGL(summ_kernel, dim3(B_ * 4), dim3(256), 0, stream, fcw, fcb, p, summ);
}

// Round 2
// 1758.755 us; speedup vs baseline: 1.1165x; 1.1165x over previous
//
#include <hip/hip_runtime.h>
#include <hip/hip_bf16.h>

// Problem: B=32, L=2048, H=1024, K=3H=3072, M=B*L=65536
// ref: t = trg @ fc_w^T + fc_b  [M, H]
//      norm1 = ||t||_2 over H   [B, L]
//      w = softmax(norm1, axis=L)
//      summ = sum_l w * t = fc_w @ (sum_l w*trg) + fc_b   (since sum_l w == 1)
// out = concat(summ [32*1024], norm1 [32*2048]) fp32

#define B_ 32
#define L_ 2048
#define H_ 1024
#define K_ 3072
#define M_ 65536

typedef __attribute__((ext_vector_type(8))) short short8;
typedef __attribute__((ext_vector_type(4))) float floatx4;

__device__ __forceinline__ unsigned int pack_bf16x2(float a, float b) {
    __hip_bfloat162 h = __float22bfloat162_rn(make_float2(a, b));
    return *reinterpret_cast<unsigned int*>(&h);
}

__device__ __forceinline__ float bf2f(unsigned short u) {
    return __uint_as_float(((unsigned int)u) << 16);
}

// async global->LDS, 16B per lane; lds dest is wave-uniform base + lane*16
__device__ __forceinline__ void gl_lds16(const unsigned short* g, unsigned short* l) {
    __builtin_amdgcn_global_load_lds(
        (const __attribute__((address_space(1))) unsigned int*)g,
        (__attribute__((address_space(3))) unsigned int*)l, 16, 0, 0);
}

// ---------------- K0: fp32 -> bf16 convert (grid-stride, 8 elems/thread/iter) --------
__global__ void __launch_bounds__(256) convert_bf16_kernel(const float* __restrict__ in,
                                                           unsigned short* __restrict__ out,
                                                           int n8) {
    int i = blockIdx.x * blockDim.x + threadIdx.x;
    const int stride = gridDim.x * blockDim.x;
    for (; i < n8; i += stride) {
        const float4* pp = (const float4*)in + (size_t)i * 2;
        float4 a = pp[0], b = pp[1];
        uint4 r;
        r.x = pack_bf16x2(a.x, a.y);
        r.y = pack_bf16x2(a.z, a.w);
        r.z = pack_bf16x2(b.x, b.y);
        r.w = pack_bf16x2(b.z, b.w);
        ((uint4*)out)[i] = r;
    }
}

// ---------------- K1 (primary): bf16 GEMM via global_load_lds, fused row-sumsq -------
// m97 structure: 128x128 tile, BK=32, contiguous LDS (rows of 32 bf16 = 64B),
// 2-barrier K-loop, staging via global_load_lds width=16 (zero VALU cost).
// XCD swizzle: bids in a group of 64 with equal bid%8 share mblk -> the 8 column
// siblings of one A row-tile run on ONE XCD and share its L2 (A fetched ~once).
__global__ void __launch_bounds__(256, 4) gemm_norm_bf_kernel(
        const unsigned short* __restrict__ A,   // trg bf16 [M_, K_]
        const unsigned short* __restrict__ Bw,  // fcw bf16 [H_, K_]
        const float* __restrict__ fcb,          // [H_]
        float* __restrict__ normsq) {
    __shared__ unsigned short As[128 * 32];
    __shared__ unsigned short Bs[128 * 32];

    const int tid = threadIdx.x;
    const int bid = blockIdx.x;
    const int group  = bid >> 6;
    const int lane64 = bid & 63;
    const int xcd    = lane64 & 7;
    const int nblk   = lane64 >> 3;   // 0..7
    const int mblk   = group * 8 + xcd;
    const int R0 = mblk * 128;
    const int N0 = nblk * 128;

    const int wv = tid >> 6, lane = tid & 63;
    const int wr = wv >> 1, wc = wv & 1;
    const int q = lane >> 4, ln = lane & 15;

    // staging: each wave issues 2 A + 2 B global_load_lds (1KB each = 16 rows)
    const int r0    = wv * 32;       // first row of this wave's 32-row slab
    const int lrow  = lane >> 2;     // 0..15
    const int lchnk = lane & 3;      // 16B chunk in row
    const unsigned short* agp = A  + (size_t)(R0 + r0 + lrow) * K_ + lchnk * 8;
    const unsigned short* bgp = Bw + (size_t)(N0 + r0 + lrow) * K_ + lchnk * 8;
    unsigned short* alds0 = &As[r0 * 32];
    unsigned short* alds1 = &As[(r0 + 16) * 32];
    unsigned short* blds0 = &Bs[r0 * 32];
    unsigned short* blds1 = &Bs[(r0 + 16) * 32];
    const size_t roff = (size_t)16 * K_;

    // prologue: stage k0 = 0
    gl_lds16(agp, alds0);
    gl_lds16(agp + roff, alds1);
    gl_lds16(bgp, blds0);
    gl_lds16(bgp + roff, blds1);

    floatx4 acc[4][4] = {};
    const unsigned short* Af = &As[(wr * 64 + ln) * 32 + q * 8];
    const unsigned short* Bf = &Bs[(wc * 64 + ln) * 32 + q * 8];

    for (int step = 0; step < 96; ++step) {
        __syncthreads();  // barrier drains vmcnt: this step's tile resident in LDS

        short8 af[4], bf[4];
#pragma unroll
        for (int i = 0; i < 4; ++i) {
            af[i] = *(const short8*)(Af + i * 16 * 32);
            bf[i] = *(const short8*)(Bf + i * 16 * 32);
        }

        __syncthreads();  // all waves done reading LDS before next-step overwrite

        if (step < 95) {
            const int kk = (step + 1) * 32;
            gl_lds16(agp + kk, alds0);
            gl_lds16(agp + roff + kk, alds1);
            gl_lds16(bgp + kk, blds0);
            gl_lds16(bgp + roff + kk, blds1);
        }

#pragma unroll
        for (int mi = 0; mi < 4; ++mi)
#pragma unroll
            for (int ni = 0; ni < 4; ++ni)
                acc[mi][ni] = __builtin_amdgcn_mfma_f32_16x16x32_bf16(af[mi], bf[ni],
                                                                      acc[mi][ni], 0, 0, 0);
    }

    // epilogue: add bias, per-row sum of squares over this block's 128 cols
    // D layout: col = ln, row = q*4 + reg
    float bz[4];
#pragma unroll
    for (int ni = 0; ni < 4; ++ni) bz[ni] = fcb[N0 + wc * 64 + ni * 16 + ln];

    float* nsq = normsq + R0 + wr * 64;
#pragma unroll
    for (int mi = 0; mi < 4; ++mi) {
#pragma unroll
        for (int r = 0; r < 4; ++r) {
            float s = 0.0f;
#pragma unroll
            for (int ni = 0; ni < 4; ++ni) {
                float v = acc[mi][ni][r] + bz[ni];
                s += v * v;
            }
            s += __shfl_xor(s, 1);
            s += __shfl_xor(s, 2);
            s += __shfl_xor(s, 4);
            s += __shfl_xor(s, 8);
            if (ln == 0) atomicAdd(&nsq[mi * 16 + q * 4 + r], s);
        }
    }
}

// ---------------- K1 (fallback): fp32-input GEMM with in-kernel convert -------------
#define LDST 40
__global__ void __launch_bounds__(256) gemm_norm_f32_kernel(const float* __restrict__ trg,
                                                            const float* __restrict__ fcw,
                                                            const float* __restrict__ fcb,
                                                            float* __restrict__ normsq) {
    __shared__ unsigned short As[128 * LDST];
    __shared__ unsigned short Bs[128 * LDST];

    const int tid  = threadIdx.x;
    const int bid  = blockIdx.x;
    const int group  = bid >> 6;
    const int lane64 = bid & 63;
    const int nblk   = lane64 >> 3;
    const int mblk   = group * 8 + (lane64 & 7);
    const int R0   = mblk * 128;
    const int N0   = nblk * 128;
    const int wv   = tid >> 6;
    const int lane = tid & 63;
    const int wr   = wv >> 1;
    const int wc   = wv & 1;
    const int q    = lane >> 4;
    const int ln   = lane & 15;

    floatx4 acc[4][4] = {};

    const int srow = tid >> 3;
    const int skc  = tid & 7;
    const float* ap = trg + (size_t)(R0 + srow) * K_ + skc * 4;
    const float* bp = fcw + (size_t)(N0 + srow) * K_ + skc * 4;
    unsigned short* AsW = &As[srow * LDST + skc * 4];
    unsigned short* BsW = &Bs[srow * LDST + skc * 4];

    const unsigned short* Af = &As[(wr * 64 + ln) * LDST + q * 8];
    const unsigned short* Bf = &Bs[(wc * 64 + ln) * LDST + q * 8];

    float4 ra[4], rb[4];
#pragma unroll
    for (int s = 0; s < 4; ++s) {
        ra[s] = *(const float4*)(ap + (size_t)(s * 32) * K_);
        rb[s] = *(const float4*)(bp + (size_t)(s * 32) * K_);
    }

    for (int step = 0; step < 96; ++step) {
        __syncthreads();
#pragma unroll
        for (int s = 0; s < 4; ++s) {
            uint2 ua, ub;
            ua.x = pack_bf16x2(ra[s].x, ra[s].y);
            ua.y = pack_bf16x2(ra[s].z, ra[s].w);
            ub.x = pack_bf16x2(rb[s].x, rb[s].y);
            ub.y = pack_bf16x2(rb[s].z, rb[s].w);
            *(uint2*)(AsW + s * 32 * LDST) = ua;
            *(uint2*)(BsW + s * 32 * LDST) = ub;
        }
        if (step < 95) {
            const int kk = (step + 1) * 32;
#pragma unroll
            for (int s = 0; s < 4; ++s) {
                ra[s] = *(const float4*)(ap + (size_t)(s * 32) * K_ + kk);
                rb[s] = *(const float4*)(bp + (size_t)(s * 32) * K_ + kk);
            }
        }
        __syncthreads();

        short8 af[4], bf[4];
#pragma unroll
        for (int i = 0; i < 4; ++i) {
            af[i] = *(const short8*)(Af + i * 16 * LDST);
            bf[i] = *(const short8*)(Bf + i * 16 * LDST);
        }
#pragma unroll
        for (int mi = 0; mi < 4; ++mi)
#pragma unroll
            for (int ni = 0; ni < 4; ++ni)
                acc[mi][ni] = __builtin_amdgcn_mfma_f32_16x16x32_bf16(af[mi], bf[ni],
                                                                      acc[mi][ni], 0, 0, 0);
    }

    float bz[4];
#pragma unroll
    for (int ni = 0; ni < 4; ++ni) bz[ni] = fcb[N0 + wc * 64 + ni * 16 + ln];

    float* nsq = normsq + R0;
#pragma unroll
    for (int mi = 0; mi < 4; ++mi) {
#pragma unroll
        for (int r = 0; r < 4; ++r) {
            float s = 0.0f;
#pragma unroll
            for (int ni = 0; ni < 4; ++ni) {
                float v = acc[mi][ni][r] + bz[ni];
                s += v * v;
            }
            s += __shfl_xor(s, 1);
            s += __shfl_xor(s, 2);
            s += __shfl_xor(s, 4);
            s += __shfl_xor(s, 8);
            if (ln == 0) atomicAdd(&nsq[wr * 64 + mi * 16 + q * 4 + r], s);
        }
    }
}

// ---------------- K2: norm1 = sqrt(normsq); per-batch softmax stats ----------------
__global__ void __launch_bounds__(256) softmax_stats_kernel(const float* __restrict__ normsq,
                                                            float* __restrict__ norm1,
                                                            float* __restrict__ bstats) {
    const int b = blockIdx.x;
    const int t = threadIdx.x;
    __shared__ float red[256];

    float vals[8];
    float mx = -1e30f;
#pragma unroll
    for (int i = 0; i < 8; ++i) {
        float v = sqrtf(normsq[b * L_ + i * 256 + t]);
        vals[i] = v;
        norm1[b * L_ + i * 256 + t] = v;
        mx = fmaxf(mx, v);
    }
    red[t] = mx;
    __syncthreads();
    for (int s = 128; s > 0; s >>= 1) {
        if (t < s) red[t] = fmaxf(red[t], red[t + s]);
        __syncthreads();
    }
    mx = red[0];
    __syncthreads();

    float sm = 0.0f;
#pragma unroll
    for (int i = 0; i < 8; ++i) sm += expf(vals[i] - mx);
    red[t] = sm;
    __syncthreads();
    for (int s = 128; s > 0; s >>= 1) {
        if (t < s) red[t] += red[t + s];
        __syncthreads();
    }
    if (t == 0) {
        bstats[b * 2 + 0] = mx;
        bstats[b * 2 + 1] = 1.0f / red[0];
    }
}

// ---------------- K3 (primary): p[b,k] = sum_l w[b,l] * trg_bf16[b,l,k] -------------
// grid 32*48: b x 16 L-chunks(128) x 3 K-chunks(1024)
__global__ void __launch_bounds__(256) pool_bf_kernel(const unsigned short* __restrict__ trgbf,
                                                      const float* __restrict__ norm1,
                                                      const float* __restrict__ bstats,
                                                      float* __restrict__ p) {
    const int t  = threadIdx.x;
    const int b  = blockIdx.x / 48;
    const int r  = blockIdx.x % 48;
    const int lc = r / 3;
    const int kc = r % 3;
    const int l0 = lc * 128;

    __shared__ float wl[128];
    if (t < 128) {
        const float mx   = bstats[b * 2 + 0];
        const float sinv = bstats[b * 2 + 1];
        wl[t] = expf(norm1[b * L_ + l0 + t] - mx) * sinv;
    }
    __syncthreads();

    const int k = kc * 1024 + t * 4;
    const unsigned short* tp = trgbf + (size_t)(b * L_ + l0) * K_ + k;
    float4 acc = {0.0f, 0.0f, 0.0f, 0.0f};
    for (int i = 0; i < 128; ++i) {
        ushort4 v = *(const ushort4*)(tp + (size_t)i * K_);
        float w = wl[i];
        acc.x += w * bf2f(v.x);
        acc.y += w * bf2f(v.y);
        acc.z += w * bf2f(v.z);
        acc.w += w * bf2f(v.w);
    }
    float* pp = p + b * K_ + k;
    atomicAdd(&pp[0], acc.x);
    atomicAdd(&pp[1], acc.y);
    atomicAdd(&pp[2], acc.z);
    atomicAdd(&pp[3], acc.w);
}

// ---------------- K3 (fallback): fp32 pool ----------------
__global__ void __launch_bounds__(256) pool_f32_kernel(const float* __restrict__ trg,
                                                       const float* __restrict__ norm1,
                                                       const float* __restrict__ bstats,
                                                       float* __restrict__ p) {
    const int t  = threadIdx.x;
    const int b  = blockIdx.x / 24;
    const int r  = blockIdx.x % 24;
    const int lc = r / 3;
    const int kc = r % 3;
    const int l0 = lc * 256;

    __shared__ float wl[256];
    const float mx   = bstats[b * 2 + 0];
    const float sinv = bstats[b * 2 + 1];
    wl[t] = expf(norm1[b * L_ + l0 + t] - mx) * sinv;
    __syncthreads();

    const int k = kc * 1024 + t * 4;
    const float* tp = trg + (size_t)b * L_ * K_ + (size_t)l0 * K_ + k;
    float4 acc = {0.0f, 0.0f, 0.0f, 0.0f};
    for (int i = 0; i < 256; ++i) {
        float4 v = *(const float4*)(tp + (size_t)i * K_);
        float w = wl[i];
        acc.x += w * v.x;
        acc.y += w * v.y;
        acc.z += w * v.z;
        acc.w += w * v.w;
    }
    float* pp = p + b * K_ + k;
    atomicAdd(&pp[0], acc.x);
    atomicAdd(&pp[1], acc.y);
    atomicAdd(&pp[2], acc.z);
    atomicAdd(&pp[3], acc.w);
}

// ---------------- K4: summ[b,h] = fc_b[h] + fc_w[h,:] . p[b,:] ----------------
__global__ void __launch_bounds__(256) summ_kernel(const float* __restrict__ fcw,
                                                   const float* __restrict__ fcb,
                                                   const float* __restrict__ p,
                                                   float* __restrict__ summ) {
    __shared__ float ps[K_];
    const int b  = blockIdx.x >> 2;
    const int hc = blockIdx.x & 3;
    const int t  = threadIdx.x;

    for (int i = t; i < K_ / 4; i += 256)
        ((float4*)ps)[i] = ((const float4*)(p + (size_t)b * K_))[i];
    __syncthreads();

    const int h = hc * 256 + t;
    const float4* wrow = (const float4*)(fcw + (size_t)h * K_);
    float acc = fcb[h];
    for (int i = 0; i < K_ / 4; ++i) {
        float4 wv = wrow[i];
        float4 pv = ((const float4*)ps)[i];
        acc += wv.x * pv.x + wv.y * pv.y + wv.z * pv.z + wv.w * pv.w;
    }
    summ[b * H_ + h] = acc;
}

extern "C" void kernel_launch(void* const* d_in, const int* in_sizes, int n_in,
                              void* d_out, int out_size, void* d_ws, size_t ws_size,
                              hipStream_t stream) {
    (void)in_sizes; (void)n_in; (void)out_size;
    const float* trg = (const float*)d_in[0];
    // d_in[1] = src, unused (n_layers == 0)
    const float* fcw = (const float*)d_in[2];
    const float* fcb = (const float*)d_in[3];

    float* out   = (float*)d_out;
    float* summ  = out;            // [32*1024]
    float* norm1 = out + B_ * H_;  // [32*2048]

    const size_t trgbf_elems = (size_t)M_ * K_;      // 201,326,592
    const size_t fcwbf_elems = (size_t)H_ * K_;      // 3,145,728
    const size_t acc_bytes   = (size_t)(M_ + B_ * K_ + 64) * sizeof(float);
    const size_t need = (trgbf_elems + fcwbf_elems) * sizeof(unsigned short) + acc_bytes;

    if (ws_size >= need) {
        // primary path: pre-convert to bf16, global_load_lds GEMM
        unsigned short* trgbf = (unsigned short*)d_ws;
        unsigned short* fcwbf = trgbf + trgbf_elems;
        float* normsq = (float*)(fcwbf + fcwbf_elems);
        float* p      = normsq + M_;
        float* bstats = p + B_ * K_;

        hipMemsetAsync(normsq, 0, acc_bytes, stream);
        hipLaunchKernelGGL(convert_bf16_kernel, dim3(16384), dim3(256), 0, stream,
                           trg, trgbf, (int)(trgbf_elems / 8));
        hipLaunchKernelGGL(convert_bf16_kernel, dim3(1536), dim3(256), 0, stream,
                           fcw, fcwbf, (int)(fcwbf_elems / 8));
        hipLaunchKernelGGL(gemm_norm_bf_kernel, dim3(4096), dim3(256), 0, stream,
                           trgbf, fcwbf, fcb, normsq);
        hipLaunchKernelGGL(softmax_stats_kernel, dim3(B_), dim3(256), 0, stream,
                           normsq, norm1, bstats);
        hipLaunchKernelGGL(pool_bf_kernel, dim3(B_ * 48), dim3(256), 0, stream,
                           trgbf, norm1, bstats, p);
        hipLaunchKernelGGL(summ_kernel, dim3(B_ * 4), dim3(256), 0, stream,
                           fcw, fcb, p, summ);
    } else {
        // fallback: fp32-input GEMM with in-kernel conversion (R1 + bias + swizzle)
        float* normsq = (float*)d_ws;
        float* p      = normsq + M_;
        float* bstats = p + B_ * K_;

        hipMemsetAsync(d_ws, 0, acc_bytes, stream);
        hipLaunchKernelGGL(gemm_norm_f32_kernel, dim3(4096), dim3(256), 0, stream,
                           trg, fcw, fcb, normsq);
        hipLaunchKernelGGL(softmax_stats_kernel, dim3(B_), dim3(256), 0, stream,
                           normsq, norm1, bstats);
        hipLaunchKernelGGL(pool_f32_kernel, dim3(B_ * 24), dim3(256), 0, stream,
                           trg, norm1, bstats, p);
        hipLaunchKernelGGL(summ_kernel, dim3(B_ * 4), dim3(256), 0, stream,
                           fcw, fcb, p, summ);
    }
}